// Round 2
// baseline (238.466 us; speedup 1.0000x reference)
//
#include <hip/hip_runtime.h>
#include <math.h>

// SPU transformer: pure elementwise, 32B read + 8B write per row, N=8.4M.
// Logical traffic fixed: 4x64 MiB read + 64 MiB write = 320 MiB.
//   -> floor at 6.29 TB/s copy ceiling = 53.3 us.
// R1: float4, regular loads: 101 us, FETCH 131 MB (L3 serves 2 of 4 streams).
// R4: NT store + 2 float4/thread: 110 us. ILP not the lever.
// R5 (best): NT loads all streams: 58.6-59.5 us. FETCH exactly 128 MiB,
//     WRITE exactly 64 MiB. Physical 3.4 TB/s, logical 5.7 TB/s.
// R6: block-granular 2x MLP/thread: 60.2-61.5 us (slight regression, FETCH
//     unchanged). Per-thread MLP confirmed not the lever (2nd time).
// R7 (this round): persistent grid-stride pipeline. 2048 blocks, 8 quads per
//     thread, explicit 1-ahead prefetch: in steady state each wave always has
//     4 NT loads in flight while computing the prior tile (compiler emits
//     counted vmcnt for this shape). Hides HBM latency WITHIN a wave
//     sustainedly instead of one-shot; kills 16k-block launch/retire churn
//     (occupancy was 66%).
// Predicted: FETCH/WRITE unchanged. Latency model: 53-55 us, VALUBusy up.
//     Neutral (~59-61) => fabric/service-rate bound => ROOFLINE next round.

typedef float nfloat4 __attribute__((ext_vector_type(4)));

__device__ __forceinline__ float spu_f(float x) {
    // x >= 0: x*x - 0.5 ; x < 0: sigmoid(-x) - 1 = 1/(1+e^x) - 1
    if (x >= 0.0f) {
        return x * x - 0.5f;
    } else {
        return 1.0f / (1.0f + __expf(x)) - 1.0f;
    }
}

__device__ __forceinline__ void spu_row(float l, float u,
                                        float p1l, float p1u,
                                        float q1l, float q1u,
                                        float b0l, float b0u,
                                        float& out_lo, float& out_hi) {
    const float sl = spu_f(l);
    const float su = spu_f(u);

    const bool neg   = (u <= 0.0f);
    const bool pos   = (l >= 0.0f);
    const bool cross = !(neg || pos);

    const float all_slopes = (su - sl) / (u - l);

    const float s0 = neg ? all_slopes : 0.0f;
    const float s1 = (pos || cross) ? all_slopes : 0.0f;

    const bool neg_slope = (all_slopes < 0.0f);
    float lo = neg_slope ? su : sl;
    float hi = neg_slope ? sl : su;
    lo = cross ? -0.5f : lo;

    float sh1 = fmaf(-s1, u, su);  // su - s1*u
    float sh0 = fmaf(-s0, l, sl);  // sl - s0*l
    sh0 = cross ? -0.5f : sh0;
    sh1 = neg ? sl : sh1;

    const float s1p = fmaxf(s1, 0.0f), s1n = fminf(s1, 0.0f);
    const float s0p = fmaxf(s0, 0.0f), s0n = fminf(s0, 0.0f);

    const float UBM = s1p * p1u + s1n * p1l;
    const float UBV = s1p * q1u + sh1 + s1n * q1l;
    const float LBM = s0p * p1l + s0n * p1u;
    const float LBV = s0n * q1l + sh0 + s0p * q1u;

    const float lower = fmaxf(LBM, 0.0f) * b0l + fminf(LBM, 0.0f) * b0u + LBV;
    const float upper = fmaxf(UBM, 0.0f) * b0u + fminf(UBM, 0.0f) * b0l + UBV;

    out_lo = (lower > lo) ? lower : lo;
    out_hi = (upper < hi) ? upper : hi;
}

__device__ __forceinline__ nfloat4 spu_quad(const nfloat4 b, const nfloat4 sp,
                                            const nfloat4 sh, const nfloat4 bp) {
    float o0, o1, o2, o3;
    spu_row(b.x, b.y, sp.x, sp.y, sh.x, sh.y, bp.x, bp.y, o0, o1);
    spu_row(b.z, b.w, sp.z, sp.w, sh.z, sh.w, bp.z, bp.w, o2, o3);
    nfloat4 o;
    o.x = o0; o.y = o1; o.z = o2; o.w = o3;
    return o;
}

__global__ __launch_bounds__(256) void SPUTransformer_62002147885333_kernel(
    const nfloat4* __restrict__ bounds,
    const nfloat4* __restrict__ slopes_prev,
    const nfloat4* __restrict__ shifts_prev,
    const nfloat4* __restrict__ bounds_prev,
    nfloat4* __restrict__ out,
    int nquads)  // nquads = N/2; one float4 = two (l,u) rows
{
    const int stride = gridDim.x * blockDim.x;
    int i = blockIdx.x * blockDim.x + threadIdx.x;
    if (i >= nquads) return;

    // Prologue: load tile 0.
    nfloat4 b  = __builtin_nontemporal_load(&bounds[i]);
    nfloat4 sp = __builtin_nontemporal_load(&slopes_prev[i]);
    nfloat4 sh = __builtin_nontemporal_load(&shifts_prev[i]);
    nfloat4 bp = __builtin_nontemporal_load(&bounds_prev[i]);

    while (true) {
        const int inext = i + stride;
        const bool have_next = (inext < nquads);

        // Prefetch next tile BEFORE computing the current one: 4 loads stay
        // in flight under the compute (counted vmcnt, no full drain).
        nfloat4 bn, spn, shn, bpn;
        if (have_next) {
            bn  = __builtin_nontemporal_load(&bounds[inext]);
            spn = __builtin_nontemporal_load(&slopes_prev[inext]);
            shn = __builtin_nontemporal_load(&shifts_prev[inext]);
            bpn = __builtin_nontemporal_load(&bounds_prev[inext]);
        }

        const nfloat4 o = spu_quad(b, sp, sh, bp);
        __builtin_nontemporal_store(o, &out[i]);

        if (!have_next) break;
        b = bn; sp = spn; sh = shn; bp = bpn;
        i = inext;
    }
}

extern "C" void kernel_launch(void* const* d_in, const int* in_sizes, int n_in,
                              void* d_out, int out_size, void* d_ws, size_t ws_size,
                              hipStream_t stream) {
    // Inputs (setup_inputs order): bounds (N,2), slopes_prev (N,2),
    // shifts_prev (N,2), bounds_prev (N,2) -- all float32.
    const nfloat4* bounds      = (const nfloat4*)d_in[0];
    const nfloat4* slopes_prev = (const nfloat4*)d_in[1];
    const nfloat4* shifts_prev = (const nfloat4*)d_in[2];
    const nfloat4* bounds_prev = (const nfloat4*)d_in[3];
    nfloat4* out = (nfloat4*)d_out;

    const int n_rows = in_sizes[0] / 2;   // N
    const int nquads = n_rows / 2;        // N even (8388608)

    const int block = 256;
    // Persistent grid: 2048 blocks (8 blocks/CU) -> 8 quads per thread at
    // N=8388608 (exactly divisible). Cap for small inputs.
    int grid = 2048;
    const long long needed = ((long long)nquads + block - 1) / block;
    if ((long long)grid > needed) grid = (int)needed;

    SPUTransformer_62002147885333_kernel<<<grid, block, 0, stream>>>(
        bounds, slopes_prev, shifts_prev, bounds_prev, out, nquads);
}

// Round 3
// 236.474 us; speedup vs baseline: 1.0084x; 1.0084x over previous
//
#include <hip/hip_runtime.h>
#include <math.h>

// SPU transformer: pure elementwise, 32B read + 8B write per row, N=8.4M.
// Logical traffic fixed: 4x64 MiB read + 64 MiB write = 320 MiB.
//   -> floor at 6.29 TB/s copy ceiling = 53.3 us.
//
// Ladder:
// R1: float4, regular loads: 101 us, FETCH 131 MB (L3 serves 2 of 4 streams).
// R4: NT store + 2 float4/thread: 110 us. Per-thread ILP not the lever.
// R5 (BEST): NT loads+stores, 1 quad/thread, 16384 blocks: 58.6-59.5 us.
//     FETCH exactly 128 MiB (2 of 4 input streams; inputs exactly fill the
//     256 MiB L3), WRITE exactly 64 MiB. Physical 3.4 TB/s, logical 5.73 TB/s
//     = 91% of the 6.29 TB/s copy ceiling.
// R6: block-granular 2x MLP/thread: 60.2-61.5 us. Regression.
// R7: persistent grid + 1-ahead software prefetch: 62.1-64.8 us, occupancy
//     DOWN to 53-58%. Regression.
//
// Conclusion: three independent latency-hiding levers (R4/R6/R7) all
// neutral-to-negative with bit-identical FETCH/WRITE. The kernel is
// service-rate bound on the XCD<->fabric path (L3 hits + HBM misses + writes
// all traverse it): 320 MiB / 58.6 us = 5.73 TB/s logical, ~91% of the
// best-known achievable copy rate. No traffic reduction is possible (every
// input byte read once, fp32 mandated by the interface).
//
// R8: exact revert to R5 (best). Predicted: 58.6-59.5 us, FETCH 131083 KB,
// WRITE 65537 KB. If reproduced => ROOFLINE.

typedef float nfloat4 __attribute__((ext_vector_type(4)));

__device__ __forceinline__ float spu_f(float x) {
    // x >= 0: x*x - 0.5 ; x < 0: sigmoid(-x) - 1 = 1/(1+e^x) - 1
    if (x >= 0.0f) {
        return x * x - 0.5f;
    } else {
        return 1.0f / (1.0f + __expf(x)) - 1.0f;
    }
}

__device__ __forceinline__ void spu_row(float l, float u,
                                        float p1l, float p1u,
                                        float q1l, float q1u,
                                        float b0l, float b0u,
                                        float& out_lo, float& out_hi) {
    const float sl = spu_f(l);
    const float su = spu_f(u);

    const bool neg   = (u <= 0.0f);
    const bool pos   = (l >= 0.0f);
    const bool cross = !(neg || pos);

    const float all_slopes = (su - sl) / (u - l);

    const float s0 = neg ? all_slopes : 0.0f;
    const float s1 = (pos || cross) ? all_slopes : 0.0f;

    const bool neg_slope = (all_slopes < 0.0f);
    float lo = neg_slope ? su : sl;
    float hi = neg_slope ? sl : su;
    lo = cross ? -0.5f : lo;

    float sh1 = fmaf(-s1, u, su);  // su - s1*u
    float sh0 = fmaf(-s0, l, sl);  // sl - s0*l
    sh0 = cross ? -0.5f : sh0;
    sh1 = neg ? sl : sh1;

    const float s1p = fmaxf(s1, 0.0f), s1n = fminf(s1, 0.0f);
    const float s0p = fmaxf(s0, 0.0f), s0n = fminf(s0, 0.0f);

    const float UBM = s1p * p1u + s1n * p1l;
    const float UBV = s1p * q1u + sh1 + s1n * q1l;
    const float LBM = s0p * p1l + s0n * p1u;
    const float LBV = s0n * q1l + sh0 + s0p * q1u;

    const float lower = fmaxf(LBM, 0.0f) * b0l + fminf(LBM, 0.0f) * b0u + LBV;
    const float upper = fmaxf(UBM, 0.0f) * b0u + fminf(UBM, 0.0f) * b0l + UBV;

    out_lo = (lower > lo) ? lower : lo;
    out_hi = (upper < hi) ? upper : hi;
}

__device__ __forceinline__ nfloat4 spu_quad(const nfloat4 b, const nfloat4 sp,
                                            const nfloat4 sh, const nfloat4 bp) {
    float o0, o1, o2, o3;
    spu_row(b.x, b.y, sp.x, sp.y, sh.x, sh.y, bp.x, bp.y, o0, o1);
    spu_row(b.z, b.w, sp.z, sp.w, sh.z, sh.w, bp.z, bp.w, o2, o3);
    nfloat4 o;
    o.x = o0; o.y = o1; o.z = o2; o.w = o3;
    return o;
}

__global__ __launch_bounds__(256) void SPUTransformer_62002147885333_kernel(
    const nfloat4* __restrict__ bounds,
    const nfloat4* __restrict__ slopes_prev,
    const nfloat4* __restrict__ shifts_prev,
    const nfloat4* __restrict__ bounds_prev,
    nfloat4* __restrict__ out,
    int npairs)  // npairs = N/2; one float4 = two (l,u) rows
{
    const int i = blockIdx.x * blockDim.x + threadIdx.x;
    if (i < npairs) {
        // Streaming loads: zero intra-kernel reuse, so skip cache allocation.
        const nfloat4 b  = __builtin_nontemporal_load(&bounds[i]);
        const nfloat4 sp = __builtin_nontemporal_load(&slopes_prev[i]);
        const nfloat4 sh = __builtin_nontemporal_load(&shifts_prev[i]);
        const nfloat4 bp = __builtin_nontemporal_load(&bounds_prev[i]);

        const nfloat4 o = spu_quad(b, sp, sh, bp);

        __builtin_nontemporal_store(o, &out[i]);
    }
}

extern "C" void kernel_launch(void* const* d_in, const int* in_sizes, int n_in,
                              void* d_out, int out_size, void* d_ws, size_t ws_size,
                              hipStream_t stream) {
    // Inputs (setup_inputs order): bounds (N,2), slopes_prev (N,2),
    // shifts_prev (N,2), bounds_prev (N,2) -- all float32.
    const nfloat4* bounds      = (const nfloat4*)d_in[0];
    const nfloat4* slopes_prev = (const nfloat4*)d_in[1];
    const nfloat4* shifts_prev = (const nfloat4*)d_in[2];
    const nfloat4* bounds_prev = (const nfloat4*)d_in[3];
    nfloat4* out = (nfloat4*)d_out;

    const int n_rows = in_sizes[0] / 2;   // N
    const int npairs = n_rows / 2;        // N even (8388608)

    const int block = 256;
    const int grid = (npairs + block - 1) / block;

    SPUTransformer_62002147885333_kernel<<<grid, block, 0, stream>>>(
        bounds, slopes_prev, shifts_prev, bounds_prev, out, npairs);
}